// Round 1
// baseline (264.355 us; speedup 1.0000x reference)
//
#include <hip/hip_runtime.h>
#include <hip/hip_bf16.h>

typedef __bf16 bf16x8 __attribute__((ext_vector_type(8)));
typedef float f32x4 __attribute__((ext_vector_type(4)));

typedef __attribute__((address_space(1))) void GAS;
typedef __attribute__((address_space(3))) void LAS;
#define GLOAD16(gp, lp) __builtin_amdgcn_global_load_lds((GAS*)(gp), (LAS*)(lp), 16, 0, 0)

#define NB 4096
#define ND 512
#define BM 128
#define BKK 32
#define NT 48          // 3 segments * (512/32)
#define NWAVE_TOT 4096 // 1024 blocks * 4 waves

// ---------------- Kernel 1: row-normalize + split into bf16 hi/lo ----------------
__global__ __launch_bounds__(256) void nrm_split_k(const float* __restrict__ x,
                                                   __bf16* __restrict__ hi,
                                                   __bf16* __restrict__ lo) {
    const int wid = threadIdx.x >> 6, lane = threadIdx.x & 63;
    const int row = blockIdx.x * 4 + wid;
    const float4* xr = reinterpret_cast<const float4*>(x + (size_t)row * ND);
    float4 v0 = xr[lane * 2 + 0];
    float4 v1 = xr[lane * 2 + 1];
    float xv[8] = {v0.x, v0.y, v0.z, v0.w, v1.x, v1.y, v1.z, v1.w};
    float ss = 0.0f;
#pragma unroll
    for (int j = 0; j < 8; ++j) ss += xv[j] * xv[j];
#pragma unroll
    for (int off = 32; off > 0; off >>= 1) ss += __shfl_xor(ss, off);
    const float rn = 1.0f / fmaxf(sqrtf(ss), 1e-12f);
    bf16x8 h, l;
#pragma unroll
    for (int j = 0; j < 8; ++j) {
        float xn = xv[j] * rn;
        __bf16 hb = (__bf16)xn;
        h[j] = hb;
        l[j] = (__bf16)(xn - (float)hb);  // exact residual (Sterbenz), then bf16 round
    }
    reinterpret_cast<bf16x8*>(hi + (size_t)row * ND)[lane] = h;
    reinterpret_cast<bf16x8*>(lo + (size_t)row * ND)[lane] = l;
}

// ------- Kernel 2: cos = hi*hi^T + hi*lo^T + lo*hi^T, fused histogram epilogue -------
__global__ __launch_bounds__(256) void gemm_stat_k(const __bf16* __restrict__ hi,
                                                   const __bf16* __restrict__ lo,
                                                   const int* __restrict__ targets,
                                                   float* __restrict__ s_part,
                                                   int* __restrict__ c_part) {
    __shared__ __align__(16) __bf16 ldsA[2][BM * BKK];
    __shared__ __align__(16) __bf16 ldsB[2][BM * BKK];
    __shared__ int tgtR[BM], tgtC[BM];

    const int bid = blockIdx.x;
    const int swz = (bid & 7) * 128 + (bid >> 3);  // XCD-aware, bijective (1024 % 8 == 0)
    const int by = swz >> 5, bx = swz & 31;
    const int row0 = by * BM, col0 = bx * BM;
    const int tid = threadIdx.x, lane = tid & 63, wid = tid >> 6;
    const int wr = wid >> 1, wc = wid & 1;

    if (tid < BM) tgtR[tid] = targets[row0 + tid];
    else          tgtC[tid - BM] = targets[col0 + tid - BM];

    // staging: 128x32 bf16 tile = 8KB = 512 x 16B chunks; 256 threads -> 2 chunks each
    const int q0 = tid, q1 = tid + 256;
    const int aoff0 = (row0 + (q0 >> 2)) * ND + (q0 & 3) * 8;
    const int aoff1 = (row0 + (q1 >> 2)) * ND + (q1 & 3) * 8;
    const int boff0 = (col0 + (q0 >> 2)) * ND + (q0 & 3) * 8;
    const int boff1 = (col0 + (q1 >> 2)) * ND + (q1 & 3) * 8;

    auto STAGE = [&](int t, int buf) {
        const int seg = t >> 4;
        const __bf16* pa = (seg == 2) ? lo : hi;  // segments: (hi,hi),(hi,lo),(lo,hi)
        const __bf16* pb = (seg == 1) ? lo : hi;
        const int kk = (t & 15) * BKK;
        GLOAD16(pa + aoff0 + kk, &ldsA[buf][q0 * 8]);
        GLOAD16(pa + aoff1 + kk, &ldsA[buf][q1 * 8]);
        GLOAD16(pb + boff0 + kk, &ldsB[buf][q0 * 8]);
        GLOAD16(pb + boff1 + kk, &ldsB[buf][q1 * 8]);
    };

    const f32x4 fzero = {0.0f, 0.0f, 0.0f, 0.0f};
    f32x4 acc[4][4];
#pragma unroll
    for (int m = 0; m < 4; ++m)
#pragma unroll
        for (int n = 0; n < 4; ++n) acc[m][n] = fzero;

    STAGE(0, 0);
    __syncthreads();

    int cur = 0;
    const int fr = lane & 15;        // fragment row (A) / col (B)
    const int kb = (lane >> 4) * 8;  // k sub-block base (elements)
    for (int t = 0; t < NT; ++t) {
        if (t + 1 < NT) STAGE(t + 1, cur ^ 1);
        bf16x8 af[4], bfv[4];
#pragma unroll
        for (int m = 0; m < 4; ++m)
            af[m] = *reinterpret_cast<const bf16x8*>(&ldsA[cur][(wr * 64 + m * 16 + fr) * BKK + kb]);
#pragma unroll
        for (int n = 0; n < 4; ++n)
            bfv[n] = *reinterpret_cast<const bf16x8*>(&ldsB[cur][(wc * 64 + n * 16 + fr) * BKK + kb]);
#pragma unroll
        for (int m = 0; m < 4; ++m)
#pragma unroll
            for (int n = 0; n < 4; ++n)
                acc[m][n] = __builtin_amdgcn_mfma_f32_16x16x32_bf16(af[m], bfv[n], acc[m][n], 0, 0, 0);
        __syncthreads();
        cur ^= 1;
    }

    // ---- epilogue: per-lane 10-bin histogram of g=|cos-label|, plus sum(g^2) per bin ----
    int trv[16], tcv[4];
    const int rbase = wr * 64 + ((lane >> 4) * 4);
#pragma unroll
    for (int m = 0; m < 4; ++m)
#pragma unroll
        for (int r = 0; r < 4; ++r) trv[m * 4 + r] = tgtR[rbase + m * 16 + r];
#pragma unroll
    for (int n = 0; n < 4; ++n) tcv[n] = tgtC[wc * 64 + n * 16 + fr];

    constexpr float E[11] = {0.0f, 0.1f, 0.2f, 0.3f, 0.4f, 0.5f,
                             0.6f, 0.7f, 0.8f, 0.9f, 1.0f + 1e-6f};
    float sacc[10]; int cacc[10];
#pragma unroll
    for (int b = 0; b < 10; ++b) { sacc[b] = 0.0f; cacc[b] = 0; }

#pragma unroll
    for (int m = 0; m < 4; ++m) {
#pragma unroll
        for (int n = 0; n < 4; ++n) {
            f32x4 v = acc[m][n];
#pragma unroll
            for (int r = 0; r < 4; ++r) {
                const float label = (trv[m * 4 + r] == tcv[n]) ? 1.0f : 0.0f;
                const float g = fabsf(v[r] - label);
                const float g2 = g * g;
                bool prev = true;  // g >= edges[0] == 0 always
#pragma unroll
                for (int b = 0; b < 10; ++b) {
                    const bool ge = (g >= E[b + 1]);
                    const bool in = prev && (!ge);  // edges[b] <= g < edges[b+1]
                    sacc[b] += in ? g2 : 0.0f;
                    cacc[b] += in ? 1 : 0;
                    prev = ge;
                }
            }
        }
    }

    // wave-reduce, one partial per wave per stat (deterministic, no atomics)
#pragma unroll
    for (int b = 0; b < 10; ++b) {
        float sv = sacc[b];
        int cv = cacc[b];
#pragma unroll
        for (int off = 32; off > 0; off >>= 1) {
            sv += __shfl_xor(sv, off);
            cv += __shfl_xor(cv, off);
        }
        if (lane == 0) {
            const int wgid = bid * 4 + wid;
            s_part[b * NWAVE_TOT + wgid] = sv;
            c_part[b * NWAVE_TOT + wgid] = cv;
        }
    }
}

// ---------------- Kernel 3: reduce partials, compute scalar loss ----------------
__global__ __launch_bounds__(256) void finalize_k(const float* __restrict__ s_part,
                                                  const int* __restrict__ c_part,
                                                  const float* __restrict__ acc_sum,
                                                  float* __restrict__ out) {
    const int tid = threadIdx.x, lane = tid & 63, wid = tid >> 6;
    float s[10]; int c[10];
#pragma unroll
    for (int b = 0; b < 10; ++b) { s[b] = 0.0f; c[b] = 0; }
    for (int i = tid; i < NWAVE_TOT; i += 256) {
#pragma unroll
        for (int b = 0; b < 10; ++b) {
            s[b] += s_part[b * NWAVE_TOT + i];
            c[b] += c_part[b * NWAVE_TOT + i];
        }
    }
#pragma unroll
    for (int b = 0; b < 10; ++b) {
#pragma unroll
        for (int off = 32; off > 0; off >>= 1) {
            s[b] += __shfl_xor(s[b], off);
            c[b] += __shfl_xor(c[b], off);
        }
    }
    __shared__ float ssh[4][10];
    __shared__ int csh[4][10];
    if (lane == 0) {
#pragma unroll
        for (int b = 0; b < 10; ++b) { ssh[wid][b] = s[b]; csh[wid][b] = c[b]; }
    }
    __syncthreads();
    if (tid == 0) {
        const float tot = 16777216.0f;  // 4096^2
        double num = 0.0, valid = 0.0;
#pragma unroll
        for (int b = 0; b < 10; ++b) {
            float sb = ssh[0][b] + ssh[1][b] + ssh[2][b] + ssh[3][b];
            int ci = csh[0][b] + csh[1][b] + csh[2][b] + csh[3][b];
            float cnt = (float)ci;                     // exact: <= 2^24
            float accn = 0.5f * acc_sum[b] + 0.5f * cnt;  // EMA, momentum=0.5
            float w = tot / (accn + 1e-6f);
            num += (double)sb * (double)w;
            valid += (double)cnt;
        }
        double loss = (valid > 0.0) ? num / valid / 16777216.0 : 0.0;
        out[0] = (float)loss;
    }
}

extern "C" void kernel_launch(void* const* d_in, const int* in_sizes, int n_in,
                              void* d_out, int out_size, void* d_ws, size_t ws_size,
                              hipStream_t stream) {
    const float* x = (const float*)d_in[0];
    const float* acc_sum = (const float*)d_in[1];
    const int* targets = (const int*)d_in[2];
    float* out = (float*)d_out;

    char* ws = (char*)d_ws;
    const size_t mat_bytes = (size_t)NB * ND * sizeof(__bf16);  // 4 MB
    __bf16* hi = (__bf16*)ws;
    __bf16* lo = (__bf16*)(ws + mat_bytes);
    float* s_part = (float*)(ws + 2 * mat_bytes);
    int* c_part = (int*)(ws + 2 * mat_bytes + 10 * NWAVE_TOT * sizeof(float));

    nrm_split_k<<<NB / 4, 256, 0, stream>>>(x, hi, lo);
    gemm_stat_k<<<(NB / BM) * (NB / BM), 256, 0, stream>>>(hi, lo, targets, s_part, c_part);
    finalize_k<<<1, 256, 0, stream>>>(s_part, c_part, acc_sum, out);
}

// Round 2
// 167.746 us; speedup vs baseline: 1.5759x; 1.5759x over previous
//
#include <hip/hip_runtime.h>
#include <hip/hip_bf16.h>

typedef __bf16 bf16x8 __attribute__((ext_vector_type(8)));
typedef float f32x4 __attribute__((ext_vector_type(4)));

typedef __attribute__((address_space(1))) void GAS;
typedef __attribute__((address_space(3))) void LAS;
#define GLOAD16(gp, lp) __builtin_amdgcn_global_load_lds((GAS*)(gp), (LAS*)(lp), 16, 0, 0)

#define NB 4096
#define ND 512
#define NKT 24  // 3 segments * (512/64) K-tiles of 64

// ---------------- Kernel 1: row-normalize + split into bf16 hi/lo; zero stats ----------------
__global__ __launch_bounds__(256) void nrm_split_k(const float* __restrict__ x,
                                                   __bf16* __restrict__ hi,
                                                   __bf16* __restrict__ lo,
                                                   float* __restrict__ stats) {
    if (blockIdx.x == 0 && threadIdx.x < 20) stats[threadIdx.x] = 0.0f;
    const int wid = threadIdx.x >> 6, lane = threadIdx.x & 63;
    const int row = blockIdx.x * 4 + wid;
    const float4* xr = reinterpret_cast<const float4*>(x + (size_t)row * ND);
    float4 v0 = xr[lane * 2 + 0];
    float4 v1 = xr[lane * 2 + 1];
    float xv[8] = {v0.x, v0.y, v0.z, v0.w, v1.x, v1.y, v1.z, v1.w};
    float ss = 0.0f;
#pragma unroll
    for (int j = 0; j < 8; ++j) ss += xv[j] * xv[j];
#pragma unroll
    for (int off = 32; off > 0; off >>= 1) ss += __shfl_xor(ss, off);
    const float rn = 1.0f / fmaxf(sqrtf(ss), 1e-12f);
    bf16x8 h, l;
#pragma unroll
    for (int j = 0; j < 8; ++j) {
        float xn = xv[j] * rn;
        __bf16 hb = (__bf16)xn;
        h[j] = hb;
        l[j] = (__bf16)(xn - (float)hb);
    }
    reinterpret_cast<bf16x8*>(hi + (size_t)row * ND)[lane] = h;
    reinterpret_cast<bf16x8*>(lo + (size_t)row * ND)[lane] = l;
}

// ------- Kernel 2: 256^2-tile 8-phase GEMM (hi*hi^T + hi*lo^T + lo*hi^T) + fused histogram -------
__global__ __launch_bounds__(512, 2) void gemm_stat_k(const __bf16* __restrict__ hi,
                                                      const __bf16* __restrict__ lo,
                                                      const int* __restrict__ targets,
                                                      float* __restrict__ stats) {
    // [slot][A=0/B=1][half][128 rows x 64 cols], rows 128B, XOR-swizzled storage
    __shared__ __align__(16) __bf16 lds[2][2][2][128 * 64];
    __shared__ int tgtR[256], tgtC[256];
    __shared__ float red_s[8][10], red_c[8][10];

    const int bid = blockIdx.x;
    const int swz = (bid & 7) * 32 + (bid >> 3);  // 256 blocks, 8 XCDs, bijective
    const int by = swz >> 4, bx = swz & 15;
    const int row0 = by * 256, col0 = bx * 256;
    const int tid = threadIdx.x, lane = tid & 63;
    const int wid = tid >> 6, wr = wid >> 2, wc = wid & 3;  // 2 x 4 waves

    if (tid < 256) tgtR[tid] = targets[row0 + tid];
    else           tgtC[tid - 256] = targets[col0 + tid - 256];

    // staging: each half-tile = 128x64 bf16 = 1024 x 16B chunks; thread handles chunks tid, tid+512
    const int c0 = tid, c1 = tid + 512;
    const int r0c = c0 >> 3, x0 = ((c0 & 7) ^ (r0c & 7)) * 8;  // inverse-swizzled source col
    const int r1c = c1 >> 3, x1 = ((c1 & 7) ^ (r1c & 7)) * 8;

    auto STAGE = [&](int s) {  // s = half-tile stream position, 0..95
        const int kt = s >> 2, h4 = s & 3;  // h4: 0,1 = A-half; 2,3 = B-half
        const int slot = kt & 1, seg = kt >> 3, kcol = (kt & 7) * 64;
        const bool isA = (h4 < 2);
        const int half = h4 & 1;
        const __bf16* mat = isA ? ((seg == 2) ? lo : hi) : ((seg == 1) ? lo : hi);
        const int brow = (isA ? row0 : col0) + half * 128;
        __bf16* ldst = &lds[slot][isA ? 0 : 1][half][0];
        GLOAD16(mat + (size_t)(brow + r0c) * ND + kcol + x0, ldst + c0 * 8);
        GLOAD16(mat + (size_t)(brow + r1c) * ND + kcol + x1, ldst + c1 * 8);
    };

    const f32x4 fzero = {0.0f, 0.0f, 0.0f, 0.0f};
    f32x4 acc[8][4];
#pragma unroll
    for (int a = 0; a < 8; ++a)
#pragma unroll
        for (int n = 0; n < 4; ++n) acc[a][n] = fzero;

    // prologue: kt0's 4 half-tiles + kt1.h0 in flight
    STAGE(0); STAGE(1); STAGE(2); STAGE(3); STAGE(4);
    asm volatile("s_waitcnt vmcnt(2)" ::: "memory");  // kt0 fully resident
    __builtin_amdgcn_s_barrier();
    __builtin_amdgcn_sched_barrier(0);

    const int fr = lane & 15, hi16 = lane >> 4;
    const int Bhalf = wc >> 1;

    for (int kt = 0; kt < NKT; ++kt) {
        const int slot = kt & 1;
        const __bf16* lA = &lds[slot][0][0][0];
        const __bf16* lB = &lds[slot][1][Bhalf][0];
#pragma unroll
        for (int f = 0; f < 4; ++f) {  // quadrant phase: (Mhalf, khalf)
            const int Mh = f >> 1, kh = f & 1;
            bf16x8 af[4], bf[4];
#pragma unroll
            for (int q = 0; q < 4; ++q) {
                const int row = wr * 64 + q * 16 + fr;
                const int cb = (kh * 64 + hi16 * 16) ^ ((row & 7) << 4);
                af[q] = *(const bf16x8*)((const char*)(lA + Mh * 8192) + row * 128 + cb);
            }
#pragma unroll
            for (int n = 0; n < 4; ++n) {
                const int row = (wc & 1) * 64 + n * 16 + fr;
                const int cb = (kh * 64 + hi16 * 16) ^ ((row & 7) << 4);
                bf[n] = *(const bf16x8*)((const char*)lB + row * 128 + cb);
            }
            const int s = 4 * kt + f + 5;  // issue 5 phases ahead
            if (s < 96) STAGE(s);
            __builtin_amdgcn_s_barrier();  // B1
            __builtin_amdgcn_sched_barrier(0);
            __builtin_amdgcn_s_setprio(1);
#pragma unroll
            for (int q = 0; q < 4; ++q)
#pragma unroll
                for (int n = 0; n < 4; ++n)
                    acc[Mh * 4 + q][n] = __builtin_amdgcn_mfma_f32_16x16x32_bf16(
                        af[q], bf[n], acc[Mh * 4 + q][n], 0, 0, 0);
            __builtin_amdgcn_s_setprio(0);
            __builtin_amdgcn_sched_barrier(0);
            if (f == 3) {  // K-tile boundary: next tile's halves must be resident
                if (kt < 22)       asm volatile("s_waitcnt vmcnt(2)" ::: "memory");
                else if (kt == 22) asm volatile("s_waitcnt vmcnt(0)" ::: "memory");
            }
            __builtin_amdgcn_s_barrier();  // B2
            __builtin_amdgcn_sched_barrier(0);
        }
    }

    // ---- epilogue: per-lane histogram of g=|cos-label| over 128 elements ----
    int tcv[4];
#pragma unroll
    for (int n = 0; n < 4; ++n) tcv[n] = tgtC[wc * 64 + n * 16 + fr];

    constexpr float E[11] = {0.0f, 0.1f, 0.2f, 0.3f, 0.4f, 0.5f,
                             0.6f, 0.7f, 0.8f, 0.9f, 1.0f + 1e-6f};
    float sacc[10], cacc[10];
#pragma unroll
    for (int b = 0; b < 10; ++b) { sacc[b] = 0.0f; cacc[b] = 0.0f; }

    const int rB = wr * 64 + hi16 * 4;
#pragma unroll
    for (int a = 0; a < 8; ++a) {
        int trv[4];
#pragma unroll
        for (int r = 0; r < 4; ++r) trv[r] = tgtR[(a >> 2) * 128 + rB + (a & 3) * 16 + r];
#pragma unroll
        for (int n = 0; n < 4; ++n) {
            f32x4 v = acc[a][n];
            const int tc = tcv[n];
#pragma unroll
            for (int r = 0; r < 4; ++r) {
                const float label = (trv[r] == tc) ? 1.0f : 0.0f;
                const float g = fabsf(v[r] - label);
                const float g2 = g * g;
                bool prev = true;
#pragma unroll
                for (int b = 0; b < 10; ++b) {
                    const bool ge = (g >= E[b + 1]);
                    const bool in = prev && (!ge);
                    sacc[b] += in ? g2 : 0.0f;
                    cacc[b] += in ? 1.0f : 0.0f;
                    prev = ge;
                }
            }
        }
    }

#pragma unroll
    for (int b = 0; b < 10; ++b) {
        float sv = sacc[b], cv = cacc[b];
#pragma unroll
        for (int off = 32; off > 0; off >>= 1) {
            sv += __shfl_xor(sv, off);
            cv += __shfl_xor(cv, off);
        }
        if (lane == 0) { red_s[wid][b] = sv; red_c[wid][b] = cv; }
    }
    __syncthreads();
    if (tid < 10) {
        float s = 0.0f, c = 0.0f;
#pragma unroll
        for (int w = 0; w < 8; ++w) { s += red_s[w][tid]; c += red_c[w][tid]; }
        atomicAdd(&stats[tid], s);
        atomicAdd(&stats[10 + tid], c);
    }
}

// ---------------- Kernel 3: tiny finalize ----------------
__global__ void finalize_k(const float* __restrict__ stats,
                           const float* __restrict__ acc_sum,
                           float* __restrict__ out) {
    if (threadIdx.x == 0) {
        const float tot = 16777216.0f;  // 4096^2
        double num = 0.0, valid = 0.0;
#pragma unroll
        for (int b = 0; b < 10; ++b) {
            float cnt = stats[10 + b];
            float accn = 0.5f * acc_sum[b] + 0.5f * cnt;
            float w = tot / (accn + 1e-6f);
            num += (double)stats[b] * (double)w;
            valid += (double)cnt;
        }
        out[0] = (valid > 0.0) ? (float)(num / valid / 16777216.0) : 0.0f;
    }
}

extern "C" void kernel_launch(void* const* d_in, const int* in_sizes, int n_in,
                              void* d_out, int out_size, void* d_ws, size_t ws_size,
                              hipStream_t stream) {
    const float* x = (const float*)d_in[0];
    const float* acc_sum = (const float*)d_in[1];
    const int* targets = (const int*)d_in[2];
    float* out = (float*)d_out;

    char* ws = (char*)d_ws;
    const size_t mat_bytes = (size_t)NB * ND * sizeof(__bf16);  // 4 MB
    __bf16* hi = (__bf16*)ws;
    __bf16* lo = (__bf16*)(ws + mat_bytes);
    float* stats = (float*)(ws + 2 * mat_bytes);  // 20 floats

    nrm_split_k<<<NB / 4, 256, 0, stream>>>(x, hi, lo, stats);
    gemm_stat_k<<<256, 512, 0, stream>>>(hi, lo, targets, stats);
    finalize_k<<<1, 64, 0, stream>>>(stats, acc_sum, out);
}